// Round 10
// baseline (331.972 us; speedup 1.0000x reference)
//
#include <hip/hip_runtime.h>
#include <hip/hip_bf16.h>

// Problem constants (B=1)
#define SEQ   2048
#define HID   2048
#define NH    16
#define NKV   2
#define DH    128
#define QKVN  2560                       // 2048 (Q) + 256 (K) + 256 (V)
#define SCALE 0.08838834764831845f      // 1/sqrt(128)
#define LOG2E 1.4426950408889634f

typedef short bf16x8 __attribute__((ext_vector_type(8)));
typedef short bf16x4 __attribute__((ext_vector_type(4)));
typedef float f32x4  __attribute__((ext_vector_type(4)));

__device__ __forceinline__ short f2bf(float x) {
    unsigned u = __float_as_uint(x);
    u += 0x7FFF + ((u >> 16) & 1);          // round-to-nearest-even
    return (short)(u >> 16);
}
__device__ __forceinline__ float bf2f(short s) {
    return __uint_as_float(((unsigned)(unsigned short)s) << 16);
}
// packed f32x2 -> bf16x2 (RTNE), single VALU op; no builtin on gfx950
__device__ __forceinline__ unsigned cvtpk(float a, float b) {
    unsigned r;
    asm("v_cvt_pk_bf16_f32 %0, %1, %2" : "=v"(r) : "v"(a), "v"(b));
    return r;
}

__device__ __forceinline__ void gl2lds16(const short* g, short* l) {
    __builtin_amdgcn_global_load_lds(
        (const __attribute__((address_space(1))) int*)g,
        (__attribute__((address_space(3))) int*)l, 16, 0, 0);
}

// ---------------------------------------------------------------------------
// All four weight transposes (fp32 [K][N] -> bf16 [N][K]) + hs fp32->bf16 copy.
// ---------------------------------------------------------------------------
__global__ void transp_all(const float* __restrict__ Wq,
                           const float* __restrict__ Wk,
                           const float* __restrict__ Wv,
                           const float* __restrict__ Wo,
                           const float* __restrict__ hs,
                           short* __restrict__ btq,   // [2560][2048]
                           short* __restrict__ wot,   // [2048][2048]
                           short* __restrict__ hsb)   // [2048][2048]
{
    const int tb = blockIdx.x;
    if (tb >= 9216) {                       // hs fp32 -> bf16, row-major copy
        int u = tb - 9216;                  // 0..2047
        const float* src = hs + (size_t)u * 2048 + threadIdx.x * 8;
        float4 f0 = *(const float4*)src;
        float4 f1 = *(const float4*)(src + 4);
        bf16x8 o = { f2bf(f0.x), f2bf(f0.y), f2bf(f0.z), f2bf(f0.w),
                     f2bf(f1.x), f2bf(f1.y), f2bf(f1.z), f2bf(f1.w) };
        *(bf16x8*)(hsb + (size_t)u * 2048 + threadIdx.x * 8) = o;
        return;
    }

    __shared__ short t[32][36];            // [col][row], +4 pad
    const float* src; short* dst; int N, bx, by;
    if (tb < 4096)      { src = Wq; dst = btq;                        N = 2048; int u = tb;        bx = (u & 63) * 32; by = (u >> 6) * 32; }
    else if (tb < 4608) { src = Wk; dst = btq + (size_t)2048 * HID;   N = 256;  int u = tb - 4096; bx = (u & 7) * 32;  by = (u >> 3) * 32; }
    else if (tb < 5120) { src = Wv; dst = btq + (size_t)2304 * HID;   N = 256;  int u = tb - 4608; bx = (u & 7) * 32;  by = (u >> 3) * 32; }
    else                { src = Wo; dst = wot;                        N = 2048; int u = tb - 5120; bx = (u & 63) * 32; by = (u >> 6) * 32; }
    const int K = HID;
    const int tid = threadIdx.x;
    {
        int row = tid >> 3, c4 = (tid & 7) * 4;    // src row (k), col group (n)
        float4 v = *(const float4*)(src + (size_t)(by + row) * N + bx + c4);
        t[c4 + 0][row] = f2bf(v.x);
        t[c4 + 1][row] = f2bf(v.y);
        t[c4 + 2][row] = f2bf(v.z);
        t[c4 + 3][row] = f2bf(v.w);
    }
    __syncthreads();
    {
        int nrow = tid >> 3, k4 = (tid & 7) * 4;   // dst row (n), col group (k)
        bf16x4 w = { t[nrow][k4], t[nrow][k4 + 1], t[nrow][k4 + 2], t[nrow][k4 + 3] };
        *(bf16x4*)(dst + (size_t)(bx + nrow) * K + by + k4) = w;
    }
}

// ---------------------------------------------------------------------------
// Unified bf16 GEMM, tile 128(M)x128(N), split-K=2 (blockIdx.z):
// each z-slice PLAIN-STORES its partial into its own buffer. No atomics.
// 2-phase double-buffered LDS (round-3 proven structure).
// ---------------------------------------------------------------------------
template<int N>
__global__ __launch_bounds__(256) void gemm_bf16(const short* __restrict__ A,
                                                 const short* __restrict__ Bt,
                                                 float* __restrict__ C0,
                                                 float* __restrict__ C1)
{
    const int K = HID;
    __shared__ short As[2][128 * 32];   // 2 x 8 KB
    __shared__ short Bs[2][128 * 32];   // 2 x 8 KB

    const int tid  = threadIdx.x;
    const int wave = tid >> 6;
    const int lane = tid & 63;
    const int quad = lane >> 4;
    const int l16  = lane & 15;
    const int m0 = blockIdx.y * 128;
    const int n0 = blockIdx.x * 128;
    const int kb0 = blockIdx.z * (K / 2);
    const int kend = kb0 + K / 2;
    const int wm = (wave >> 1) * 64;
    const int wn = (wave & 1) * 64;
    float* __restrict__ Cp = (blockIdx.z == 0) ? C0 : C1;

    const int r0 = tid >> 2;            // staging row 0..63
    const int c0 = (tid & 3) * 8;       // staging col group
    const short* gA = A  + (size_t)(m0 + r0) * K + c0;
    const short* gB = Bt + (size_t)(n0 + r0) * K + c0;
    const int so = wave * 512;          // wave-uniform LDS staging offset (shorts)

    f32x4 acc[4][4];
#pragma unroll
    for (int i = 0; i < 4; ++i)
#pragma unroll
        for (int j = 0; j < 4; ++j) acc[i][j] = (f32x4){0.f, 0.f, 0.f, 0.f};

    // prologue: stage first K-tile into buffer 0
    gl2lds16(gA + kb0,                  &As[0][so]);
    gl2lds16(gA + kb0 + (size_t)64 * K, &As[0][so + 2048]);
    gl2lds16(gB + kb0,                  &Bs[0][so]);
    gl2lds16(gB + kb0 + (size_t)64 * K, &Bs[0][so + 2048]);
    __syncthreads();

    int cur = 0;
    for (int k0 = kb0; k0 < kend; k0 += 32) {
        // issue prefetch of next K-tile into the other buffer (before compute)
        if (k0 + 32 < kend) {
            int nb = cur ^ 1;
            gl2lds16(gA + k0 + 32,                  &As[nb][so]);
            gl2lds16(gA + k0 + 32 + (size_t)64 * K, &As[nb][so + 2048]);
            gl2lds16(gB + k0 + 32,                  &Bs[nb][so]);
            gl2lds16(gB + k0 + 32 + (size_t)64 * K, &Bs[nb][so + 2048]);
        }

        const short* cA = As[cur];
        const short* cB = Bs[cur];
        bf16x8 av[4], bv[4];
#pragma unroll
        for (int mt = 0; mt < 4; ++mt)
            av[mt] = *(const bf16x8*)&cA[(wm + mt * 16 + l16) * 32 + quad * 8];
#pragma unroll
        for (int nt = 0; nt < 4; ++nt)
            bv[nt] = *(const bf16x8*)&cB[(wn + nt * 16 + l16) * 32 + quad * 8];
#pragma unroll
        for (int mt = 0; mt < 4; ++mt)
#pragma unroll
            for (int nt = 0; nt < 4; ++nt)
                acc[mt][nt] = __builtin_amdgcn_mfma_f32_16x16x32_bf16(
                    av[mt], bv[nt], acc[mt][nt], 0, 0, 0);

        __syncthreads();     // drains prefetch (vmcnt) + this tile's ds_reads
        cur ^= 1;
    }

#pragma unroll
    for (int nt = 0; nt < 4; ++nt) {
        int col = n0 + wn + nt * 16 + l16;
#pragma unroll
        for (int mt = 0; mt < 4; ++mt)
#pragma unroll
            for (int r = 0; r < 4; ++r) {
                int row = m0 + wm + mt * 16 + quad * 4 + r;
                Cp[(size_t)row * N + col] = acc[mt][nt][r];
            }
    }
}

// ---------------------------------------------------------------------------
// Fused split-K sum + bias + RoPE + layout pass, reading the two GEMM
// partial buffers. Q: sum+bias, rope, write fp32 into qA (in place).
// K: sum+bias, rope -> bf16 kbf. V: sum+bias -> bf16 transposed vtb.
// ---------------------------------------------------------------------------
__global__ void rope_cvt(float* __restrict__ qA,
                         const float* __restrict__ qB,
                         const float* __restrict__ cosp,
                         const float* __restrict__ sinp,
                         const float* __restrict__ bq,
                         const float* __restrict__ bk,
                         const float* __restrict__ bv,
                         short* __restrict__ kb,
                         short* __restrict__ vt)
{
    int g = blockIdx.x * 256 + threadIdx.x;
    if (g < SEQ * NH * 64) {                        // Q: sum + bias + RoPE in-place
        int d = g & 63;
        int h = (g >> 6) & (NH - 1);
        int s = g >> 10;
        size_t i = (size_t)s * QKVN + h * DH;
        float x0 = qA[i + d]      + qB[i + d]      + bq[h * DH + d];
        float x1 = qA[i + d + 64] + qB[i + d + 64] + bq[h * DH + d + 64];
        float c0 = cosp[s * DH + d],  c1 = cosp[s * DH + d + 64];
        float s0 = sinp[s * DH + d],  s1 = sinp[s * DH + d + 64];
        qA[i + d]      = x0 * c0 - x1 * s0;
        qA[i + d + 64] = x1 * c1 + x0 * s1;
        return;
    }
    g -= SEQ * NH * 64;
    if (g < SEQ * NKV * 64) {                       // K: sum + bias + RoPE -> bf16
        int d   = g & 63;
        int kvh = (g >> 6) & (NKV - 1);
        int s   = g >> 7;
        size_t i = (size_t)s * QKVN + NH * DH + kvh * DH;
        float x0 = qA[i + d]      + qB[i + d]      + bk[kvh * DH + d];
        float x1 = qA[i + d + 64] + qB[i + d + 64] + bk[kvh * DH + d + 64];
        float c0 = cosp[s * DH + d],  c1 = cosp[s * DH + d + 64];
        float s0 = sinp[s * DH + d],  s1 = sinp[s * DH + d + 64];
        short* ob = kb + (size_t)s * (NKV * DH) + kvh * DH;
        ob[d]      = f2bf(x0 * c0 - x1 * s0);
        ob[d + 64] = f2bf(x1 * c1 + x0 * s1);
        return;
    }
    g -= SEQ * NKV * 64;                            // V: sum + bias -> bf16 transposed
    int s   = g & (SEQ - 1);
    int d   = (g >> 11) & (DH - 1);
    int kvh = g >> 18;
    size_t i = (size_t)s * QKVN + NH * DH + NKV * DH + kvh * DH + d;
    vt[g] = f2bf(qA[i] + qB[i] + bv[kvh * DH + d]);
}

// ---------------------------------------------------------------------------
// out = A + B (fp32), vectorized. 8 floats/thread.
// ---------------------------------------------------------------------------
__global__ void add2(const float* __restrict__ A,
                     const float* __restrict__ B,
                     float* __restrict__ O)
{
    size_t g = ((size_t)blockIdx.x * 256 + threadIdx.x) * 8;
    float4 a0 = *(const float4*)(A + g);
    float4 a1 = *(const float4*)(A + g + 4);
    float4 b0 = *(const float4*)(B + g);
    float4 b1 = *(const float4*)(B + g + 4);
    float4 o0 = { a0.x + b0.x, a0.y + b0.y, a0.z + b0.z, a0.w + b0.w };
    float4 o1 = { a1.x + b1.x, a1.y + b1.y, a1.z + b1.z, a1.w + b1.w };
    *(float4*)(O + g)     = o0;
    *(float4*)(O + g + 4) = o1;
}

// ---------------------------------------------------------------------------
// MFMA flash attention, KVBLK=64: 64-key tiles halve the barrier rate and
// amortize the softmax pass over 2x keys. Key-split for qb>=16 (round-6
// scheme over 64-key tiles: chunk0=[0,T/2), chunk1=[T/2,T), T=qb+1).
// cvt_pk packed bf16, tree reductions, s_setprio around MFMA clusters.
// ---------------------------------------------------------------------------
__global__ __launch_bounds__(256) void attn_mfma(const float* __restrict__ Qp,
                                                 const short* __restrict__ Kb,
                                                 const short* __restrict__ Vtb,
                                                 short* __restrict__ ctx,
                                                 short* __restrict__ opart,
                                                 float2* __restrict__ mlbuf)
{
    __shared__ short Ks[64][136];      // 17.0 KB
    __shared__ short Vs[128][72];      // 18.0 KB
    __shared__ short Ps[4][16][72];    //  9.0 KB  per-wave [q][k=64] operand

    const int bid = blockIdx.x;
    int qb, h, kt0, kt1, slot;
    if (bid < 512) {                   // split blocks, heavy qb first
        qb = 31 - (bid >> 5);          // 31..16
        h  = (bid >> 1) & 15;
        int chunk = bid & 1;
        int T = qb + 1, Tm = T >> 1;   // 64-key tiles
        kt0 = chunk ? Tm : 0;
        kt1 = chunk ? T  : Tm;
        slot = ((qb - 16) * 16 + h) * 2 + chunk;
    } else {
        int u = bid - 512;
        qb = 15 - (u >> 4);
        h  = u & 15;
        kt0 = 0;
        kt1 = qb + 1;
        slot = -1;
    }
    const int kvh = h >> 3;
    const int tid  = threadIdx.x;
    const int wave = tid >> 6;
    const int lane = tid & 63;
    const int quad = lane >> 4;
    const int l16  = lane & 15;

    const int qrow0 = qb * 64 + wave * 16;
    const int qg    = qrow0 + l16;       // this lane's q column

    // staging coordinates: 4 x 16B chunks each for K (64x128) and V (128x64)
    int kr[4], kc[4], vd[4], vc[4];
#pragma unroll
    for (int i = 0; i < 4; ++i) {
        int cid = tid + i * 256;
        kr[i] = cid >> 4; kc[i] = (cid & 15) * 8;   // K: row=key, 16 chunks/row
        vd[i] = cid >> 3; vc[i] = (cid & 7) * 8;    // V: row=d,   8 chunks/row
    }
    const short* Kbase = Kb + kvh * DH;
    const short* Vbase = Vtb + (size_t)kvh * DH * SEQ;

    // prologue prefetch: first tile into registers
    int4 kreg[4], vreg[4];
    {
        const int kb0 = kt0 * 64;
#pragma unroll
        for (int i = 0; i < 4; ++i) {
            kreg[i] = *(const int4*)(Kbase + (size_t)(kb0 + kr[i]) * (NKV * DH) + kc[i]);
            vreg[i] = *(const int4*)(Vbase + (size_t)vd[i] * SEQ + kb0 + vc[i]);
        }
    }

    const float SL = SCALE * LOG2E;
    bf16x8 aq[4];
    {
        const float* qsrc = Qp + (size_t)(qrow0 + l16) * QKVN + h * DH + quad * 8;
#pragma unroll
        for (int c = 0; c < 4; ++c) {
            float4 f0 = *(const float4*)(qsrc + c * 32);
            float4 f1 = *(const float4*)(qsrc + c * 32 + 4);
            bf16x8 a;
            unsigned* au = (unsigned*)&a;
            au[0] = cvtpk(f0.x * SL, f0.y * SL);
            au[1] = cvtpk(f0.z * SL, f0.w * SL);
            au[2] = cvtpk(f1.x * SL, f1.y * SL);
            au[3] = cvtpk(f1.z * SL, f1.w * SL);
            aq[c] = a;
        }
    }

    f32x4 of[8];
#pragma unroll
    for (int t = 0; t < 8; ++t) of[t] = (f32x4){0.f, 0.f, 0.f, 0.f};
    float m_old = -1e30f, l_sum = 0.f;

    for (int kt = kt0; kt < kt1; ++kt) {
        const int kbase = kt * 64;
        __syncthreads();                 // previous tile's compute done
#pragma unroll
        for (int i = 0; i < 4; ++i) {
            *(int4*)&Ks[kr[i]][kc[i]] = kreg[i];
            *(int4*)&Vs[vd[i]][vc[i]] = vreg[i];
        }
        __syncthreads();                 // staged tile visible

        // prefetch next tile into registers; latency hides under compute
        if (kt + 1 < kt1) {
            const int nb = kbase + 64;
#pragma unroll
            for (int i = 0; i < 4; ++i) {
                kreg[i] = *(const int4*)(Kbase + (size_t)(nb + kr[i]) * (NKV * DH) + kc[i]);
                vreg[i] = *(const int4*)(Vbase + (size_t)vd[i] * SEQ + nb + vc[i]);
            }
        }

        if (kbase > qrow0 + 15) continue;   // wave-uniform fully-masked tile

        f32x4 s[4];
#pragma unroll
        for (int h2 = 0; h2 < 4; ++h2) s[h2] = (f32x4){0.f, 0.f, 0.f, 0.f};
        __builtin_amdgcn_s_setprio(1);
#pragma unroll
        for (int c = 0; c < 4; ++c)
#pragma unroll
            for (int h2 = 0; h2 < 4; ++h2) {
                bf16x8 ak = *(const bf16x8*)&Ks[h2 * 16 + l16][c * 32 + quad * 8];
                s[h2] = __builtin_amdgcn_mfma_f32_16x16x32_bf16(ak, aq[c], s[h2], 0, 0, 0);
            }
        __builtin_amdgcn_s_setprio(0);

        float x[16];
        if (kbase + 63 > qrow0) {           // diagonal tile: apply causal mask
#pragma unroll
            for (int h2 = 0; h2 < 4; ++h2)
#pragma unroll
                for (int r = 0; r < 4; ++r)
                    x[h2 * 4 + r] = (kbase + h2 * 16 + quad * 4 + r <= qg)
                                    ? s[h2][r] : -1e30f;
        } else {                            // interior tile: no mask needed
#pragma unroll
            for (int h2 = 0; h2 < 4; ++h2)
#pragma unroll
                for (int r = 0; r < 4; ++r) x[h2 * 4 + r] = s[h2][r];
        }

        // tree max-reduce (4-deep) then cross-lane
        float m0 = fmaxf(fmaxf(x[0], x[1]),  fmaxf(x[2], x[3]));
        float m1 = fmaxf(fmaxf(x[4], x[5]),  fmaxf(x[6], x[7]));
        float m2 = fmaxf(fmaxf(x[8], x[9]),  fmaxf(x[10], x[11]));
        float m3 = fmaxf(fmaxf(x[12], x[13]), fmaxf(x[14], x[15]));
        float mr = fmaxf(fmaxf(m0, m1), fmaxf(m2, m3));
        mr = fmaxf(mr, __shfl_xor(mr, 16));
        mr = fmaxf(mr, __shfl_xor(mr, 32));

        // defer-max (T13): only rescale when some row max grew by > 8 (exp2 dom)
        if (!__all(mr <= m_old + 8.f)) {
            float mn    = fmaxf(m_old, mr);
            float alpha = __builtin_amdgcn_exp2f(m_old - mn);
            l_sum *= alpha;
#pragma unroll
            for (int t = 0; t < 8; ++t)
#pragma unroll
                for (int r = 0; r < 4; ++r) of[t][r] *= alpha;
            m_old = mn;
        }

        float p[16];
#pragma unroll
        for (int i = 0; i < 16; ++i) p[i] = __builtin_amdgcn_exp2f(x[i] - m_old);
        float ps = (((p[0] + p[1]) + (p[2] + p[3])) + ((p[4] + p[5]) + (p[6] + p[7])))
                 + (((p[8] + p[9]) + (p[10] + p[11])) + ((p[12] + p[13]) + (p[14] + p[15])));
        ps += __shfl_xor(ps, 16);
        ps += __shfl_xor(ps, 32);
        l_sum += ps;

        // packed P -> bf16 (8 cvt_pk for 16 values)
#pragma unroll
        for (int h2 = 0; h2 < 4; ++h2)
            *(uint2*)&Ps[wave][l16][h2 * 16 + quad * 4] =
                make_uint2(cvtpk(p[h2 * 4], p[h2 * 4 + 1]),
                           cvtpk(p[h2 * 4 + 2], p[h2 * 4 + 3]));

        bf16x8 bp0 = *(const bf16x8*)&Ps[wave][l16][quad * 8];
        bf16x8 bp1 = *(const bf16x8*)&Ps[wave][l16][32 + quad * 8];
        __builtin_amdgcn_s_setprio(1);
#pragma unroll
        for (int t = 0; t < 8; ++t) {
            bf16x8 av0 = *(const bf16x8*)&Vs[t * 16 + l16][quad * 8];
            bf16x8 av1 = *(const bf16x8*)&Vs[t * 16 + l16][32 + quad * 8];
            of[t] = __builtin_amdgcn_mfma_f32_16x16x32_bf16(av0, bp0, of[t], 0, 0, 0);
            of[t] = __builtin_amdgcn_mfma_f32_16x16x32_bf16(av1, bp1, of[t], 0, 0, 0);
        }
        __builtin_amdgcn_s_setprio(0);
    }

    float inv = 1.f / l_sum;
    if (slot < 0) {
        short* dst = ctx + (size_t)qg * HID + h * DH + quad * 4;
#pragma unroll
        for (int t = 0; t < 8; ++t) {
            *(uint2*)(dst + t * 16) =
                make_uint2(cvtpk(of[t][0] * inv, of[t][1] * inv),
                           cvtpk(of[t][2] * inv, of[t][3] * inv));
        }
    } else {
        int qlocal = wave * 16 + l16;
        short* dst = opart + (size_t)slot * 8192 + qlocal * 128 + quad * 4;
#pragma unroll
        for (int t = 0; t < 8; ++t) {
            *(uint2*)(dst + t * 16) =
                make_uint2(cvtpk(of[t][0] * inv, of[t][1] * inv),
                           cvtpk(of[t][2] * inv, of[t][3] * inv));
        }
        if (quad == 0) mlbuf[slot * 64 + qlocal] = make_float2(m_old, l_sum);
    }
}

// ---------------------------------------------------------------------------
// Merge two key-chunk partials per (qb>=16, h) into ctx.
// ---------------------------------------------------------------------------
__global__ void attn_merge(const short* __restrict__ opart,
                           const float2* __restrict__ mlbuf,
                           short* __restrict__ ctx)
{
    const int qb = 16 + (blockIdx.x >> 4);
    const int h  = blockIdx.x & 15;
    const int s0 = ((qb - 16) * 16 + h) * 2;
    const int s1 = s0 + 1;
    const int t  = threadIdx.x;
    const int r  = t >> 2;            // q-row local 0..63
    const int c0 = (t & 3) * 32;      // 32 d-cols

    float2 a = mlbuf[s0 * 64 + r];
    float2 b = mlbuf[s1 * 64 + r];
    float mm = fmaxf(a.x, b.x);
    float w0 = __builtin_amdgcn_exp2f(a.x - mm) * a.y;
    float w1 = __builtin_amdgcn_exp2f(b.x - mm) * b.y;
    float inv = 1.f / (w0 + w1);
    w0 *= inv; w1 *= inv;

    const short* p0 = opart + (size_t)s0 * 8192 + r * 128 + c0;
    const short* p1 = opart + (size_t)s1 * 8192 + r * 128 + c0;
    short* dst = ctx + (size_t)(qb * 64 + r) * HID + h * DH + c0;
#pragma unroll
    for (int i = 0; i < 8; ++i) {
        bf16x4 v0 = *(const bf16x4*)(p0 + i * 4);
        bf16x4 v1 = *(const bf16x4*)(p1 + i * 4);
        bf16x4 o;
#pragma unroll
        for (int j = 0; j < 4; ++j)
            o[j] = f2bf(w0 * bf2f(v0[j]) + w1 * bf2f(v1[j]));
        *(bf16x4*)(dst + i * 4) = o;
    }
}

// ---------------------------------------------------------------------------
extern "C" void kernel_launch(void* const* d_in, const int* in_sizes, int n_in,
                              void* d_out, int out_size, void* d_ws, size_t ws_size,
                              hipStream_t stream)
{
    const float* hs   = (const float*)d_in[0];
    const float* cosp = (const float*)d_in[1];
    const float* sinp = (const float*)d_in[2];
    const float* Wq = (const float*)d_in[4];
    const float* bq = (const float*)d_in[5];
    const float* Wk = (const float*)d_in[6];
    const float* bk = (const float*)d_in[7];
    const float* Wv = (const float*)d_in[8];
    const float* bv = (const float*)d_in[9];
    const float* Wo = (const float*)d_in[10];
    float* out = (float*)d_out;

    char* w = (char*)d_ws;
    short*  wot   = (short*)w;   w += (size_t)HID * HID * 2;           //  8 MB [transp -> gemm_wo]
    float*  qkvA  = (float*)w;   w += (size_t)SEQ * QKVN * 4;          // 20 MB [gemm_qkv -> rope -> attn(Q)]
    short*  kbf   = (short*)w;   w += (size_t)SEQ * (NKV * DH) * 2;    //  1 MB [rope -> attn]
    short*  vtb   = (short*)w;   w += (size_t)NKV * DH * SEQ * 2;      //  1 MB [rope -> attn]
    short*  ctxb  = (short*)w;   w += (size_t)SEQ * HID * 2;           //  8 MB [attn -> gemm_wo]
    short*  opart = (short*)w;   w += (size_t)512 * 8192 * 2;          //  8 MB [attn -> merge]
    float2* mlbuf = (float2*)w;  w += (size_t)512 * 64 * sizeof(float2); // 256 KB
    // time-aliased pool (38 MB): {btq, hsb, qkvB} die before gemm_wo runs,
    // then the region is reused for the Wo split-K partials.
    char* pool = w;
    short* btq  = (short*)pool;                                        // 10 MB [transp -> gemm_qkv]
    short* hsb  = (short*)(pool + (size_t)QKVN * HID * 2);             //  8 MB [transp -> gemm_qkv]
    float* qkvB = (float*)(pool + (size_t)QKVN * HID * 2
                                + (size_t)SEQ * HID * 2);              // 20 MB [gemm_qkv -> rope]
    float* woA  = (float*)pool;                                        // 16 MB [gemm_wo -> add2]
    float* woB  = (float*)(pool + (size_t)HID * HID * 4);              // 16 MB [gemm_wo -> add2]

    // 1. weight transposes (fp32 [K][N] -> bf16 [N][K]) + hs -> bf16
    transp_all<<<11264, 256, 0, stream>>>(Wq, Wk, Wv, Wo, hs, btq, wot, hsb);

    // 2. QKV projection, split-K=2, plain stores into two partial buffers
    gemm_bf16<QKVN><<<dim3(QKVN / 128, SEQ / 128, 2), 256, 0, stream>>>(hsb, btq, qkvA, qkvB);

    // 3. split-K sum + bias + RoPE Q/K + V transpose, one launch
    {
        int total = SEQ * NH * 64 + SEQ * NKV * 64 + NKV * DH * SEQ;
        rope_cvt<<<total / 256, 256, 0, stream>>>(qkvA, qkvB, cosp, sinp, bq, bk, bv, kbf, vtb);
    }

    // 4. attention: KVBLK=64, key-split for qb>=16, then merge
    attn_mfma<<<768, 256, 0, stream>>>(qkvA, kbf, vtb, ctxb, opart, mlbuf);
    attn_merge<<<256, 256, 0, stream>>>(opart, mlbuf, ctxb);

    // 5. output projection, split-K=2, plain stores into two partial buffers
    gemm_bf16<HID><<<dim3(HID / 128, SEQ / 128, 2), 256, 0, stream>>>(ctxb, wot, woA, woB);

    // 6. out = woA + woB
    add2<<<(HID * HID) / (256 * 8), 256, 0, stream>>>(woA, woB, out);
}

// Round 11
// 263.307 us; speedup vs baseline: 1.2608x; 1.2608x over previous
//
#include <hip/hip_runtime.h>
#include <hip/hip_bf16.h>

// Problem constants (B=1)
#define SEQ   2048
#define HID   2048
#define NH    16
#define NKV   2
#define DH    128
#define QKVN  2560                       // 2048 (Q) + 256 (K) + 256 (V)
#define SCALE 0.08838834764831845f      // 1/sqrt(128)
#define LOG2E 1.4426950408889634f

typedef short bf16x8 __attribute__((ext_vector_type(8)));
typedef short bf16x4 __attribute__((ext_vector_type(4)));
typedef float f32x4  __attribute__((ext_vector_type(4)));

__device__ __forceinline__ short f2bf(float x) {
    unsigned u = __float_as_uint(x);
    u += 0x7FFF + ((u >> 16) & 1);          // round-to-nearest-even
    return (short)(u >> 16);
}
__device__ __forceinline__ float bf2f(short s) {
    return __uint_as_float(((unsigned)(unsigned short)s) << 16);
}
// packed f32x2 -> bf16x2 (RTNE), single VALU op; no builtin on gfx950
__device__ __forceinline__ unsigned cvtpk(float a, float b) {
    unsigned r;
    asm("v_cvt_pk_bf16_f32 %0, %1, %2" : "=v"(r) : "v"(a), "v"(b));
    return r;
}

__device__ __forceinline__ void gl2lds16(const short* g, short* l) {
    __builtin_amdgcn_global_load_lds(
        (const __attribute__((address_space(1))) int*)g,
        (__attribute__((address_space(3))) int*)l, 16, 0, 0);
}

// ---------------------------------------------------------------------------
// All four weight transposes (fp32 [K][N] -> bf16 [N][K]) + hs fp32->bf16 copy.
// ---------------------------------------------------------------------------
__global__ void transp_all(const float* __restrict__ Wq,
                           const float* __restrict__ Wk,
                           const float* __restrict__ Wv,
                           const float* __restrict__ Wo,
                           const float* __restrict__ hs,
                           short* __restrict__ btq,   // [2560][2048]
                           short* __restrict__ wot,   // [2048][2048]
                           short* __restrict__ hsb)   // [2048][2048]
{
    const int tb = blockIdx.x;
    if (tb >= 9216) {                       // hs fp32 -> bf16, row-major copy
        int u = tb - 9216;                  // 0..2047
        const float* src = hs + (size_t)u * 2048 + threadIdx.x * 8;
        float4 f0 = *(const float4*)src;
        float4 f1 = *(const float4*)(src + 4);
        bf16x8 o = { f2bf(f0.x), f2bf(f0.y), f2bf(f0.z), f2bf(f0.w),
                     f2bf(f1.x), f2bf(f1.y), f2bf(f1.z), f2bf(f1.w) };
        *(bf16x8*)(hsb + (size_t)u * 2048 + threadIdx.x * 8) = o;
        return;
    }

    __shared__ short t[32][36];            // [col][row], +4 pad
    const float* src; short* dst; int N, bx, by;
    if (tb < 4096)      { src = Wq; dst = btq;                        N = 2048; int u = tb;        bx = (u & 63) * 32; by = (u >> 6) * 32; }
    else if (tb < 4608) { src = Wk; dst = btq + (size_t)2048 * HID;   N = 256;  int u = tb - 4096; bx = (u & 7) * 32;  by = (u >> 3) * 32; }
    else if (tb < 5120) { src = Wv; dst = btq + (size_t)2304 * HID;   N = 256;  int u = tb - 4608; bx = (u & 7) * 32;  by = (u >> 3) * 32; }
    else                { src = Wo; dst = wot;                        N = 2048; int u = tb - 5120; bx = (u & 63) * 32; by = (u >> 6) * 32; }
    const int K = HID;
    const int tid = threadIdx.x;
    {
        int row = tid >> 3, c4 = (tid & 7) * 4;    // src row (k), col group (n)
        float4 v = *(const float4*)(src + (size_t)(by + row) * N + bx + c4);
        t[c4 + 0][row] = f2bf(v.x);
        t[c4 + 1][row] = f2bf(v.y);
        t[c4 + 2][row] = f2bf(v.z);
        t[c4 + 3][row] = f2bf(v.w);
    }
    __syncthreads();
    {
        int nrow = tid >> 3, k4 = (tid & 7) * 4;   // dst row (n), col group (k)
        bf16x4 w = { t[nrow][k4], t[nrow][k4 + 1], t[nrow][k4 + 2], t[nrow][k4 + 3] };
        *(bf16x4*)(dst + (size_t)(bx + nrow) * K + by + k4) = w;
    }
}

// ---------------------------------------------------------------------------
// Unified bf16 GEMM, tile 128(M)x128(N), split-K=2 (blockIdx.z):
// each z-slice PLAIN-STORES its partial into its own buffer. No atomics.
// 2-phase double-buffered LDS (round-3 proven structure).
// ---------------------------------------------------------------------------
template<int N>
__global__ __launch_bounds__(256) void gemm_bf16(const short* __restrict__ A,
                                                 const short* __restrict__ Bt,
                                                 float* __restrict__ C0,
                                                 float* __restrict__ C1)
{
    const int K = HID;
    __shared__ short As[2][128 * 32];   // 2 x 8 KB
    __shared__ short Bs[2][128 * 32];   // 2 x 8 KB

    const int tid  = threadIdx.x;
    const int wave = tid >> 6;
    const int lane = tid & 63;
    const int quad = lane >> 4;
    const int l16  = lane & 15;
    const int m0 = blockIdx.y * 128;
    const int n0 = blockIdx.x * 128;
    const int kb0 = blockIdx.z * (K / 2);
    const int kend = kb0 + K / 2;
    const int wm = (wave >> 1) * 64;
    const int wn = (wave & 1) * 64;
    float* __restrict__ Cp = (blockIdx.z == 0) ? C0 : C1;

    const int r0 = tid >> 2;            // staging row 0..63
    const int c0 = (tid & 3) * 8;       // staging col group
    const short* gA = A  + (size_t)(m0 + r0) * K + c0;
    const short* gB = Bt + (size_t)(n0 + r0) * K + c0;
    const int so = wave * 512;          // wave-uniform LDS staging offset (shorts)

    f32x4 acc[4][4];
#pragma unroll
    for (int i = 0; i < 4; ++i)
#pragma unroll
        for (int j = 0; j < 4; ++j) acc[i][j] = (f32x4){0.f, 0.f, 0.f, 0.f};

    // prologue: stage first K-tile into buffer 0
    gl2lds16(gA + kb0,                  &As[0][so]);
    gl2lds16(gA + kb0 + (size_t)64 * K, &As[0][so + 2048]);
    gl2lds16(gB + kb0,                  &Bs[0][so]);
    gl2lds16(gB + kb0 + (size_t)64 * K, &Bs[0][so + 2048]);
    __syncthreads();

    int cur = 0;
    for (int k0 = kb0; k0 < kend; k0 += 32) {
        // issue prefetch of next K-tile into the other buffer (before compute)
        if (k0 + 32 < kend) {
            int nb = cur ^ 1;
            gl2lds16(gA + k0 + 32,                  &As[nb][so]);
            gl2lds16(gA + k0 + 32 + (size_t)64 * K, &As[nb][so + 2048]);
            gl2lds16(gB + k0 + 32,                  &Bs[nb][so]);
            gl2lds16(gB + k0 + 32 + (size_t)64 * K, &Bs[nb][so + 2048]);
        }

        const short* cA = As[cur];
        const short* cB = Bs[cur];
        bf16x8 av[4], bv[4];
#pragma unroll
        for (int mt = 0; mt < 4; ++mt)
            av[mt] = *(const bf16x8*)&cA[(wm + mt * 16 + l16) * 32 + quad * 8];
#pragma unroll
        for (int nt = 0; nt < 4; ++nt)
            bv[nt] = *(const bf16x8*)&cB[(wn + nt * 16 + l16) * 32 + quad * 8];
#pragma unroll
        for (int mt = 0; mt < 4; ++mt)
#pragma unroll
            for (int nt = 0; nt < 4; ++nt)
                acc[mt][nt] = __builtin_amdgcn_mfma_f32_16x16x32_bf16(
                    av[mt], bv[nt], acc[mt][nt], 0, 0, 0);

        __syncthreads();     // drains prefetch (vmcnt) + this tile's ds_reads
        cur ^= 1;
    }

#pragma unroll
    for (int nt = 0; nt < 4; ++nt) {
        int col = n0 + wn + nt * 16 + l16;
#pragma unroll
        for (int mt = 0; mt < 4; ++mt)
#pragma unroll
            for (int r = 0; r < 4; ++r) {
                int row = m0 + wm + mt * 16 + quad * 4 + r;
                Cp[(size_t)row * N + col] = acc[mt][nt][r];
            }
    }
}

// ---------------------------------------------------------------------------
// Fused split-K sum + bias + RoPE + layout pass, reading the two GEMM
// partial buffers. Q: sum+bias, rope, PRE-SCALED (SCALE*LOG2E) -> bf16 qbf.
// K: sum+bias, rope -> bf16 kbf. V: sum+bias -> bf16 transposed vtb.
// ---------------------------------------------------------------------------
__global__ void rope_cvt(const float* __restrict__ qA,
                         const float* __restrict__ qB,
                         const float* __restrict__ cosp,
                         const float* __restrict__ sinp,
                         const float* __restrict__ bq,
                         const float* __restrict__ bk,
                         const float* __restrict__ bv,
                         short* __restrict__ qbf,
                         short* __restrict__ kb,
                         short* __restrict__ vt)
{
    const float SL = SCALE * LOG2E;
    int g = blockIdx.x * 256 + threadIdx.x;
    if (g < SEQ * NH * 64) {                        // Q: sum+bias+RoPE -> scaled bf16
        int d = g & 63;
        int h = (g >> 6) & (NH - 1);
        int s = g >> 10;
        size_t i = (size_t)s * QKVN + h * DH;
        float x0 = qA[i + d]      + qB[i + d]      + bq[h * DH + d];
        float x1 = qA[i + d + 64] + qB[i + d + 64] + bq[h * DH + d + 64];
        float c0 = cosp[s * DH + d],  c1 = cosp[s * DH + d + 64];
        float s0 = sinp[s * DH + d],  s1 = sinp[s * DH + d + 64];
        short* ob = qbf + (size_t)s * HID + h * DH;
        ob[d]      = f2bf((x0 * c0 - x1 * s0) * SL);
        ob[d + 64] = f2bf((x1 * c1 + x0 * s1) * SL);
        return;
    }
    g -= SEQ * NH * 64;
    if (g < SEQ * NKV * 64) {                       // K: sum + bias + RoPE -> bf16
        int d   = g & 63;
        int kvh = (g >> 6) & (NKV - 1);
        int s   = g >> 7;
        size_t i = (size_t)s * QKVN + NH * DH + kvh * DH;
        float x0 = qA[i + d]      + qB[i + d]      + bk[kvh * DH + d];
        float x1 = qA[i + d + 64] + qB[i + d + 64] + bk[kvh * DH + d + 64];
        float c0 = cosp[s * DH + d],  c1 = cosp[s * DH + d + 64];
        float s0 = sinp[s * DH + d],  s1 = sinp[s * DH + d + 64];
        short* ob = kb + (size_t)s * (NKV * DH) + kvh * DH;
        ob[d]      = f2bf(x0 * c0 - x1 * s0);
        ob[d + 64] = f2bf(x1 * c1 + x0 * s1);
        return;
    }
    g -= SEQ * NKV * 64;                            // V: sum + bias -> bf16 transposed
    int s   = g & (SEQ - 1);
    int d   = (g >> 11) & (DH - 1);
    int kvh = g >> 18;
    size_t i = (size_t)s * QKVN + NH * DH + NKV * DH + kvh * DH + d;
    vt[g] = f2bf(qA[i] + qB[i] + bv[kvh * DH + d]);
}

// ---------------------------------------------------------------------------
// out = A + B (fp32), vectorized. 8 floats/thread.
// ---------------------------------------------------------------------------
__global__ void add2(const float* __restrict__ A,
                     const float* __restrict__ B,
                     float* __restrict__ O)
{
    size_t g = ((size_t)blockIdx.x * 256 + threadIdx.x) * 8;
    float4 a0 = *(const float4*)(A + g);
    float4 a1 = *(const float4*)(A + g + 4);
    float4 b0 = *(const float4*)(B + g);
    float4 b1 = *(const float4*)(B + g + 4);
    float4 o0 = { a0.x + b0.x, a0.y + b0.y, a0.z + b0.z, a0.w + b0.w };
    float4 o1 = { a1.x + b1.x, a1.y + b1.y, a1.z + b1.z, a1.w + b1.w };
    *(float4*)(O + g)     = o0;
    *(float4*)(O + g + 4) = o1;
}

// ---------------------------------------------------------------------------
// MFMA flash attention with key-split for heavy q-blocks (round-6 grid).
// Round-11: Q read directly as pre-scaled bf16 (prologue cvt removed);
// cvt_pk packed bf16, tree reductions, s_setprio around MFMA clusters.
// ---------------------------------------------------------------------------
__global__ __launch_bounds__(256) void attn_mfma(const short* __restrict__ Qb,
                                                 const short* __restrict__ Kb,
                                                 const short* __restrict__ Vtb,
                                                 short* __restrict__ ctx,
                                                 short* __restrict__ opart,
                                                 float2* __restrict__ mlbuf)
{
    __shared__ short Ks[32][136];
    __shared__ short Vs[128][40];
    __shared__ short Ps[4][16][40];    // per-wave [q][k] operand layout

    const int bid = blockIdx.x;
    int qb, h, kt0, kt1, slot;
    if (bid < 512) {                   // split blocks, heavy qb first
        qb = 31 - (bid >> 5);          // 31..16
        h  = (bid >> 1) & 15;
        int chunk = bid & 1;
        int half  = qb + 1;            // 32-key tiles per chunk
        kt0 = chunk * half;
        kt1 = kt0 + half;
        slot = ((qb - 16) * 16 + h) * 2 + chunk;
    } else {
        int u = bid - 512;
        qb = 15 - (u >> 4);
        h  = u & 15;
        kt0 = 0;
        kt1 = (qb + 1) * 2;
        slot = -1;
    }
    const int kvh = h >> 3;
    const int tid  = threadIdx.x;
    const int wave = tid >> 6;
    const int lane = tid & 63;
    const int quad = lane >> 4;
    const int l16  = lane & 15;

    const int qrow0 = qb * 64 + wave * 16;
    const int qg    = qrow0 + l16;       // this lane's q column

    // staging coordinates (two 16B chunks per thread for K and for V)
    const int cid1  = tid + 256;
    const int kr_r0 = tid  >> 4, kr_c0 = (tid  & 15) * 8;
    const int kr_r1 = cid1 >> 4, kr_c1 = (cid1 & 15) * 8;
    const int vd0   = tid  >> 2, vc0   = (tid  & 3) * 8;
    const int vd1   = cid1 >> 2, vc1   = (cid1 & 3) * 8;
    const short* Kbase = Kb + kvh * DH;
    const short* Vbase = Vtb + (size_t)kvh * DH * SEQ;

    // prologue prefetch: first tile into registers
    int4 kA, kB, vA, vB;
    {
        const int kb0 = kt0 * 32;
        kA = *(const int4*)(Kbase + (size_t)(kb0 + kr_r0) * (NKV * DH) + kr_c0);
        kB = *(const int4*)(Kbase + (size_t)(kb0 + kr_r1) * (NKV * DH) + kr_c1);
        vA = *(const int4*)(Vbase + (size_t)vd0 * SEQ + kb0 + vc0);
        vB = *(const int4*)(Vbase + (size_t)vd1 * SEQ + kb0 + vc1);
    }

    // Q fragments: direct pre-scaled bf16 loads (no conversion needed)
    bf16x8 aq[4];
    {
        const short* qsrc = Qb + (size_t)(qrow0 + l16) * HID + h * DH + quad * 8;
#pragma unroll
        for (int c = 0; c < 4; ++c)
            aq[c] = *(const bf16x8*)(qsrc + c * 32);
    }

    f32x4 of[8];
#pragma unroll
    for (int t = 0; t < 8; ++t) of[t] = (f32x4){0.f, 0.f, 0.f, 0.f};
    float m_old = -1e30f, l_sum = 0.f;

    for (int kt = kt0; kt < kt1; ++kt) {
        const int kbase = kt * 32;
        __syncthreads();                 // previous tile's compute done
        *(int4*)&Ks[kr_r0][kr_c0] = kA;
        *(int4*)&Ks[kr_r1][kr_c1] = kB;
        *(int4*)&Vs[vd0][vc0]     = vA;
        *(int4*)&Vs[vd1][vc1]     = vB;
        __syncthreads();                 // staged tile visible

        // prefetch next tile into registers; latency hides under compute
        if (kt + 1 < kt1) {
            const int nb = kbase + 32;
            kA = *(const int4*)(Kbase + (size_t)(nb + kr_r0) * (NKV * DH) + kr_c0);
            kB = *(const int4*)(Kbase + (size_t)(nb + kr_r1) * (NKV * DH) + kr_c1);
            vA = *(const int4*)(Vbase + (size_t)vd0 * SEQ + nb + vc0);
            vB = *(const int4*)(Vbase + (size_t)vd1 * SEQ + nb + vc1);
        }

        if (kbase > qrow0 + 15) continue;   // wave-uniform fully-masked tile

        f32x4 s0 = (f32x4){0.f, 0.f, 0.f, 0.f};
        f32x4 s1 = (f32x4){0.f, 0.f, 0.f, 0.f};
        __builtin_amdgcn_s_setprio(1);
#pragma unroll
        for (int c = 0; c < 4; ++c) {
            bf16x8 ak0 = *(const bf16x8*)&Ks[l16][c * 32 + quad * 8];
            bf16x8 ak1 = *(const bf16x8*)&Ks[16 + l16][c * 32 + quad * 8];
            s0 = __builtin_amdgcn_mfma_f32_16x16x32_bf16(ak0, aq[c], s0, 0, 0, 0);
            s1 = __builtin_amdgcn_mfma_f32_16x16x32_bf16(ak1, aq[c], s1, 0, 0, 0);
        }
        __builtin_amdgcn_s_setprio(0);

        float x[8];
        if (kbase + 31 > qrow0) {           // diagonal tile: apply causal mask
#pragma unroll
            for (int r = 0; r < 4; ++r) {
                x[r]     = (kbase + quad * 4 + r      <= qg) ? s0[r] : -1e30f;
                x[4 + r] = (kbase + 16 + quad * 4 + r <= qg) ? s1[r] : -1e30f;
            }
        } else {                            // interior tile: no mask needed
#pragma unroll
            for (int r = 0; r < 4; ++r) { x[r] = s0[r]; x[4 + r] = s1[r]; }
        }

        // tree max-reduce (3-deep) then cross-lane
        float mr = fmaxf(fmaxf(fmaxf(x[0], x[1]), fmaxf(x[2], x[3])),
                         fmaxf(fmaxf(x[4], x[5]), fmaxf(x[6], x[7])));
        mr = fmaxf(mr, __shfl_xor(mr, 16));
        mr = fmaxf(mr, __shfl_xor(mr, 32));

        // defer-max (T13): only rescale when some row max grew by > 8 (exp2 dom)
        if (!__all(mr <= m_old + 8.f)) {
            float mn    = fmaxf(m_old, mr);
            float alpha = __builtin_amdgcn_exp2f(m_old - mn);
            l_sum *= alpha;
#pragma unroll
            for (int t = 0; t < 8; ++t)
#pragma unroll
                for (int r = 0; r < 4; ++r) of[t][r] *= alpha;
            m_old = mn;
        }

        float p[8];
#pragma unroll
        for (int i = 0; i < 8; ++i) p[i] = __builtin_amdgcn_exp2f(x[i] - m_old);
        float ps = ((p[0] + p[1]) + (p[2] + p[3])) + ((p[4] + p[5]) + (p[6] + p[7]));
        ps += __shfl_xor(ps, 16);
        ps += __shfl_xor(ps, 32);
        l_sum += ps;

        // packed P -> bf16 (4 cvt_pk replaces 8 manual f2bf chains)
        *(uint2*)&Ps[wave][l16][quad * 4] =
            make_uint2(cvtpk(p[0], p[1]), cvtpk(p[2], p[3]));
        *(uint2*)&Ps[wave][l16][16 + quad * 4] =
            make_uint2(cvtpk(p[4], p[5]), cvtpk(p[6], p[7]));

        bf16x8 bp = *(const bf16x8*)&Ps[wave][l16][quad * 8];
        __builtin_amdgcn_s_setprio(1);
#pragma unroll
        for (int t = 0; t < 8; ++t) {
            bf16x8 av = *(const bf16x8*)&Vs[t * 16 + l16][quad * 8];
            of[t] = __builtin_amdgcn_mfma_f32_16x16x32_bf16(av, bp, of[t], 0, 0, 0);
        }
        __builtin_amdgcn_s_setprio(0);
    }

    float inv = 1.f / l_sum;
    if (slot < 0) {
        short* dst = ctx + (size_t)qg * HID + h * DH + quad * 4;
#pragma unroll
        for (int t = 0; t < 8; ++t) {
            *(uint2*)(dst + t * 16) =
                make_uint2(cvtpk(of[t][0] * inv, of[t][1] * inv),
                           cvtpk(of[t][2] * inv, of[t][3] * inv));
        }
    } else {
        int qlocal = wave * 16 + l16;
        short* dst = opart + (size_t)slot * 8192 + qlocal * 128 + quad * 4;
#pragma unroll
        for (int t = 0; t < 8; ++t) {
            *(uint2*)(dst + t * 16) =
                make_uint2(cvtpk(of[t][0] * inv, of[t][1] * inv),
                           cvtpk(of[t][2] * inv, of[t][3] * inv));
        }
        if (quad == 0) mlbuf[slot * 64 + qlocal] = make_float2(m_old, l_sum);
    }
}

// ---------------------------------------------------------------------------
// Merge two key-chunk partials per (qb>=16, h) into ctx.
// ---------------------------------------------------------------------------
__global__ void attn_merge(const short* __restrict__ opart,
                           const float2* __restrict__ mlbuf,
                           short* __restrict__ ctx)
{
    const int qb = 16 + (blockIdx.x >> 4);
    const int h  = blockIdx.x & 15;
    const int s0 = ((qb - 16) * 16 + h) * 2;
    const int s1 = s0 + 1;
    const int t  = threadIdx.x;
    const int r  = t >> 2;            // q-row local 0..63
    const int c0 = (t & 3) * 32;      // 32 d-cols

    float2 a = mlbuf[s0 * 64 + r];
    float2 b = mlbuf[s1 * 64 + r];
    float mm = fmaxf(a.x, b.x);
    float w0 = __builtin_amdgcn_exp2f(a.x - mm) * a.y;
    float w1 = __builtin_amdgcn_exp2f(b.x - mm) * b.y;
    float inv = 1.f / (w0 + w1);
    w0 *= inv; w1 *= inv;

    const short* p0 = opart + (size_t)s0 * 8192 + r * 128 + c0;
    const short* p1 = opart + (size_t)s1 * 8192 + r * 128 + c0;
    short* dst = ctx + (size_t)(qb * 64 + r) * HID + h * DH + c0;
#pragma unroll
    for (int i = 0; i < 8; ++i) {
        bf16x4 v0 = *(const bf16x4*)(p0 + i * 4);
        bf16x4 v1 = *(const bf16x4*)(p1 + i * 4);
        bf16x4 o;
#pragma unroll
        for (int j = 0; j < 4; ++j)
            o[j] = f2bf(w0 * bf2f(v0[j]) + w1 * bf2f(v1[j]));
        *(bf16x4*)(dst + i * 4) = o;
    }
}

// ---------------------------------------------------------------------------
extern "C" void kernel_launch(void* const* d_in, const int* in_sizes, int n_in,
                              void* d_out, int out_size, void* d_ws, size_t ws_size,
                              hipStream_t stream)
{
    const float* hs   = (const float*)d_in[0];
    const float* cosp = (const float*)d_in[1];
    const float* sinp = (const float*)d_in[2];
    const float* Wq = (const float*)d_in[4];
    const float* bq = (const float*)d_in[5];
    const float* Wk = (const float*)d_in[6];
    const float* bk = (const float*)d_in[7];
    const float* Wv = (const float*)d_in[8];
    const float* bv = (const float*)d_in[9];
    const float* Wo = (const float*)d_in[10];
    float* out = (float*)d_out;

    char* w = (char*)d_ws;
    short*  wot   = (short*)w;   w += (size_t)HID * HID * 2;           //  8 MB [transp -> gemm_wo]
    float*  qkvA  = (float*)w;   w += (size_t)SEQ * QKVN * 4;          // 20 MB [gemm_qkv -> rope]
    short*  kbf   = (short*)w;   w += (size_t)SEQ * (NKV * DH) * 2;    //  1 MB [rope -> attn]
    short*  vtb   = (short*)w;   w += (size_t)NKV * DH * SEQ * 2;      //  1 MB [rope -> attn]
    short*  ctxb  = (short*)w;   w += (size_t)SEQ * HID * 2;           //  8 MB [attn -> gemm_wo]
    short*  opart = (short*)w;   w += (size_t)512 * 8192 * 2;          //  8 MB [attn -> merge]
    float2* mlbuf = (float2*)w;  w += (size_t)512 * 64 * sizeof(float2); // 256 KB
    // time-aliased pool (38 MB), sequential lifetimes:
    //   phase 1 (transp/gemm_qkv): btq 10 MB | hsb 8 MB | qkvB 20 MB
    //   phase 2 (rope -> attn):    qbf 8 MB reuses btq space (btq dead;
    //                              no overlap with qkvB at pool+18 MB)
    //   phase 3 (gemm_wo/add2):    woA 16 MB | woB 16 MB
    char* pool = w;
    short* btq  = (short*)pool;                                        // 10 MB [transp -> gemm_qkv]
    short* qbf  = (short*)pool;                                        //  8 MB [rope -> attn]
    short* hsb  = (short*)(pool + (size_t)QKVN * HID * 2);             //  8 MB [transp -> gemm_qkv]
    float* qkvB = (float*)(pool + (size_t)QKVN * HID * 2
                                + (size_t)SEQ * HID * 2);              // 20 MB [gemm_qkv -> rope]
    float* woA  = (float*)pool;                                        // 16 MB [gemm_wo -> add2]
    float* woB  = (float*)(pool + (size_t)HID * HID * 4);              // 16 MB [gemm_wo -> add2]

    // 1. weight transposes (fp32 [K][N] -> bf16 [N][K]) + hs -> bf16
    transp_all<<<11264, 256, 0, stream>>>(Wq, Wk, Wv, Wo, hs, btq, wot, hsb);

    // 2. QKV projection, split-K=2, plain stores into two partial buffers
    gemm_bf16<QKVN><<<dim3(QKVN / 128, SEQ / 128, 2), 256, 0, stream>>>(hsb, btq, qkvA, qkvB);

    // 3. split-K sum + bias + RoPE; Q -> pre-scaled bf16 qbf, K -> kbf, V -> vtb
    {
        int total = SEQ * NH * 64 + SEQ * NKV * 64 + NKV * DH * SEQ;
        rope_cvt<<<total / 256, 256, 0, stream>>>(qkvA, qkvB, cosp, sinp, bq, bk, bv,
                                                  qbf, kbf, vtb);
    }

    // 4. attention: key-split for qb>=16 (round-6 decomposition), then merge
    attn_mfma<<<768, 256, 0, stream>>>(qbf, kbf, vtb, ctxb, opart, mlbuf);
    attn_merge<<<256, 256, 0, stream>>>(opart, mlbuf, ctxb);

    // 5. output projection, split-K=2, plain stores into two partial buffers
    gemm_bf16<HID><<<dim3(HID / 128, SEQ / 128, 2), 256, 0, stream>>>(ctxb, wot, woA, woB);

    // 6. out = woA + woB
    add2<<<(HID * HID) / (256 * 8), 256, 0, stream>>>(woA, woB, out);
}